// Round 1
// baseline (2159.050 us; speedup 1.0000x reference)
//
#include <hip/hip_runtime.h>
#include <stdint.h>

// GEMM: C[M,N] = A[M,K] * W[N,K]^T + bias,  M=8192 (seq*batch), N=16384, K=4096
#define M_DIM 8192
#define N_DIM 16384
#define K_DIM 4096

#define BM 128
#define BN 128
#define BK 32

typedef __bf16   bf16x8 __attribute__((ext_vector_type(8)));
typedef float    f32x4  __attribute__((ext_vector_type(4)));
typedef uint16_t u16x8  __attribute__((ext_vector_type(8)));

__device__ __forceinline__ uint16_t f2bf(float f) {
    union { float f; uint32_t u; } v; v.f = f;
    uint32_t u = v.u;
    // round-to-nearest-even bf16
    return (uint16_t)((u + 0x7FFFu + ((u >> 16) & 1u)) >> 16);
}

// f32 -> bf16 conversion, vectorized 4-wide, grid-stride
__global__ void __launch_bounds__(256) cvt_kernel(const float* __restrict__ src,
                                                  uint16_t* __restrict__ dst, int n4) {
    int i = blockIdx.x * 256 + threadIdx.x;
    const int stride = gridDim.x * 256;
    for (; i < n4; i += stride) {
        float4 f = ((const float4*)src)[i];
        ushort4 o = make_ushort4(f2bf(f.x), f2bf(f.y), f2bf(f.z), f2bf(f.w));
        ((ushort4*)dst)[i] = o;
    }
}

// async global->LDS, 16B per lane. LDS dest is wave-uniform base + lane*16:
// our chunk index is linear in tid, so lane order matches LDS order exactly.
__device__ __forceinline__ void gload16(const uint16_t* g, uint16_t* lds) {
    __builtin_amdgcn_global_load_lds(
        (const __attribute__((address_space(1))) uint32_t*)g,
        (__attribute__((address_space(3))) uint32_t*)lds, 16, 0, 0);
}

// fallback staging: load 8 f32, convert, one ds_write_b128
__device__ __forceinline__ void stage_cvt(const float* __restrict__ g, uint16_t* lds) {
    float4 f0 = *(const float4*)g;
    float4 f1 = *(const float4*)(g + 4);
    u16x8 o;
    o[0] = f2bf(f0.x); o[1] = f2bf(f0.y); o[2] = f2bf(f0.z); o[3] = f2bf(f0.w);
    o[4] = f2bf(f1.x); o[5] = f2bf(f1.y); o[6] = f2bf(f1.z); o[7] = f2bf(f1.w);
    *(u16x8*)lds = o;
}

// m97-structure GEMM: 128x128 block tile, BK=32, 4 waves of 64x64 (4x4 MFMA 16x16x32)
template <bool CVT>
__global__ void __launch_bounds__(256, 2)
gemm_kernel(const void* __restrict__ Ap, const void* __restrict__ Bp,
            const float* __restrict__ bias, float* __restrict__ C) {
    __shared__ alignas(16) uint16_t As[BM * BK];
    __shared__ alignas(16) uint16_t Bs[BN * BK];

    const int tid  = threadIdx.x;
    const int lane = tid & 63;
    const int wave = tid >> 6;
    const int wr   = wave >> 1;   // wave row (0..1) -> 64 rows
    const int wc   = wave & 1;    // wave col (0..1) -> 64 cols
    const long m0  = (long)blockIdx.y * BM;
    const long n0  = (long)blockIdx.x * BN;

    // staging: 2 chunks of 8 elems per thread per tile (512 chunks = 128x32)
    const int c1  = tid + 256;
    const int ar0 = tid >> 2, ac0 = (tid & 3) * 8;
    const int ar1 = c1 >> 2,  ac1 = (c1 & 3) * 8;

    f32x4 acc[4][4];
    const f32x4 fzero = {0.f, 0.f, 0.f, 0.f};
#pragma unroll
    for (int i = 0; i < 4; ++i)
#pragma unroll
        for (int j = 0; j < 4; ++j) acc[i][j] = fzero;

    // MFMA fragment addressing: A[m=lane&15][k=(lane>>4)*8 + j]
    const int frow = lane & 15;
    const int fk   = (lane >> 4) * 8;

    for (int k0 = 0; k0 < K_DIM; k0 += BK) {
        if constexpr (!CVT) {
            const uint16_t* A = (const uint16_t*)Ap;
            const uint16_t* B = (const uint16_t*)Bp;
            gload16(A + (m0 + ar0) * K_DIM + k0 + ac0, &As[tid * 8]);
            gload16(A + (m0 + ar1) * K_DIM + k0 + ac1, &As[c1 * 8]);
            gload16(B + (n0 + ar0) * K_DIM + k0 + ac0, &Bs[tid * 8]);
            gload16(B + (n0 + ar1) * K_DIM + k0 + ac1, &Bs[c1 * 8]);
        } else {
            const float* A = (const float*)Ap;
            const float* B = (const float*)Bp;
            stage_cvt(A + (m0 + ar0) * K_DIM + k0 + ac0, &As[tid * 8]);
            stage_cvt(A + (m0 + ar1) * K_DIM + k0 + ac1, &As[c1 * 8]);
            stage_cvt(B + (n0 + ar0) * K_DIM + k0 + ac0, &Bs[tid * 8]);
            stage_cvt(B + (n0 + ar1) * K_DIM + k0 + ac1, &Bs[c1 * 8]);
        }
        __syncthreads();

        bf16x8 af[4], bfr[4];
#pragma unroll
        for (int t = 0; t < 4; ++t) {
            af[t]  = *(const bf16x8*)&As[(wr * 64 + t * 16 + frow) * BK + fk];
            bfr[t] = *(const bf16x8*)&Bs[(wc * 64 + t * 16 + frow) * BK + fk];
        }
#pragma unroll
        for (int i = 0; i < 4; ++i)
#pragma unroll
            for (int j = 0; j < 4; ++j)
                acc[i][j] = __builtin_amdgcn_mfma_f32_16x16x32_bf16(
                    af[i], bfr[j], acc[i][j], 0, 0, 0);
        __syncthreads();
    }

    // epilogue: C/D layout col=lane&15, row=(lane>>4)*4+reg
    const int cr = (lane >> 4) * 4;
    const int cc = lane & 15;
    float bb[4];
#pragma unroll
    for (int j = 0; j < 4; ++j) bb[j] = bias[n0 + wc * 64 + j * 16 + cc];
#pragma unroll
    for (int i = 0; i < 4; ++i) {
        const long grow = m0 + wr * 64 + i * 16 + cr;
#pragma unroll
        for (int j = 0; j < 4; ++j) {
            const long gcol = n0 + wc * 64 + j * 16 + cc;
#pragma unroll
            for (int r = 0; r < 4; ++r)
                C[(grow + r) * N_DIM + gcol] = acc[i][j][r] + bb[j];
        }
    }
}

extern "C" void kernel_launch(void* const* d_in, const int* in_sizes, int n_in,
                              void* d_out, int out_size, void* d_ws, size_t ws_size,
                              hipStream_t stream) {
    const float* x    = (const float*)d_in[0];
    const float* w    = (const float*)d_in[1];
    const float* bias = (const float*)d_in[2];
    float* out        = (float*)d_out;

    const size_t xe   = (size_t)M_DIM * K_DIM;  // 33.5M elems
    const size_t we   = (size_t)N_DIM * K_DIM;  // 67.1M elems
    const size_t need = (xe + we) * sizeof(uint16_t);  // 192 MiB

    dim3 grid(N_DIM / BN, M_DIM / BM);
    if (ws_size >= need) {
        uint16_t* xb = (uint16_t*)d_ws;
        uint16_t* wb = xb + xe;
        cvt_kernel<<<4096, 256, 0, stream>>>(x, xb, (int)(xe / 4));
        cvt_kernel<<<8192, 256, 0, stream>>>(w, wb, (int)(we / 4));
        gemm_kernel<false><<<grid, 256, 0, stream>>>(xb, wb, bias, out);
    } else {
        // workspace too small: convert f32->bf16 inline during LDS staging
        gemm_kernel<true><<<grid, 256, 0, stream>>>(x, w, bias, out);
    }
}